// Round 5
// baseline (760.236 us; speedup 1.0000x reference)
//
#include <hip/hip_runtime.h>

#define BN_EPS 1e-5f

using bfrag = __attribute__((ext_vector_type(8))) short;
using f32x4 = __attribute__((ext_vector_type(4))) float;

__device__ inline float bf2f(unsigned int h16) {
    union { unsigned int u; float f; } v; v.u = h16 << 16; return v.f;
}
__device__ inline unsigned short f2bf(float f) {
    union { float f; unsigned int u; } v; v.f = f;
    unsigned int u = v.u;
    u += 0x7fffu + ((u >> 16) & 1u);
    return (unsigned short)(u >> 16);
}
__device__ inline void unpack8(uint4 u, float* f) {
    f[0] = bf2f(u.x & 0xffffu); f[1] = bf2f(u.x >> 16);
    f[2] = bf2f(u.y & 0xffffu); f[3] = bf2f(u.y >> 16);
    f[4] = bf2f(u.z & 0xffffu); f[5] = bf2f(u.z >> 16);
    f[6] = bf2f(u.w & 0xffffu); f[7] = bf2f(u.w >> 16);
}
__device__ inline void fma8(uint4 G, float w, float* acc) {
    float v[8];
    unpack8(G, v);
#pragma unroll
    for (int k = 0; k < 8; ++k) acc[k] += w * v[k];
}

// ---------------- CSR build ----------------

__global__ void count_kernel(const int* __restrict__ ei, int E, int* __restrict__ cnt) {
    int e = blockIdx.x * blockDim.x + threadIdx.x;
    if (e < E) atomicAdd(&cnt[ei[E + e]], 1);
}

__global__ void dinv_kernel(const int* __restrict__ cnt, float* __restrict__ dinv, int N) {
    int i = blockIdx.x * blockDim.x + threadIdx.x;
    if (i < N) dinv[i] = rsqrtf((float)(cnt[i] + 1));  // +1 self loop
}

__global__ __launch_bounds__(1024) void scan_blocks(const int* __restrict__ cnt,
                                                    int* __restrict__ rowptr,
                                                    int* __restrict__ bsum, int N) {
    __shared__ int sh[1024];
    int t = threadIdx.x;
    int i = blockIdx.x * 1024 + t;
    int v = (i < N) ? cnt[i] : 0;
    sh[t] = v;
    __syncthreads();
    for (int off = 1; off < 1024; off <<= 1) {
        int x = (t >= off) ? sh[t - off] : 0;
        __syncthreads();
        sh[t] += x;
        __syncthreads();
    }
    if (i < N) rowptr[i] = sh[t] - v;
    if (t == 1023) bsum[blockIdx.x] = sh[1023];
}

__global__ void scan_carry(const int* __restrict__ bsum, int* __restrict__ boff, int nblk) {
    if (threadIdx.x == 0 && blockIdx.x == 0) {
        int run = 0;
        for (int b = 0; b < nblk; ++b) { int v = bsum[b]; boff[b] = run; run += v; }
        boff[nblk] = run;
    }
}

__global__ void scan_add(int* __restrict__ rowptr, const int* __restrict__ boff,
                         int* __restrict__ cursor, int N, int nblk) {
    int i = blockIdx.x * blockDim.x + threadIdx.x;
    if (i < N) {
        int v = rowptr[i] + boff[i >> 10];
        rowptr[i] = v;
        cursor[i] = v;
    }
    if (i == 0) rowptr[N] = boff[nblk];
}

__global__ void fill_kernel(const int* __restrict__ ei, int E, int* __restrict__ cursor,
                            const float* __restrict__ dinv, int2* __restrict__ epack) {
    int e = blockIdx.x * blockDim.x + threadIdx.x;
    if (e < E) {
        int s = ei[e], d = ei[E + e];
        int p = atomicAdd(&cursor[d], 1);
        float nrm = dinv[s] * dinv[d];
        epack[p] = make_int2(s, __float_as_int(nrm));
    }
}

__global__ void s_kernel(const int* __restrict__ rowptr, const int2* __restrict__ epack,
                         const float* __restrict__ dinv, float* __restrict__ sarr, int N) {
    int i = blockIdx.x * blockDim.x + threadIdx.x;
    if (i < N) {
        float a = dinv[i] * dinv[i];
        int j1 = rowptr[i + 1];
        for (int j = rowptr[i]; j < j1; ++j) a += __int_as_float(epack[j].y);
        sarr[i] = a;
    }
}

// ---------------- per-layer weight prep: Wt[j][k] = bf16(scale[k]*W[k][j]), c[j]=shift@W ----------------

template <bool HASBN>
__global__ __launch_bounds__(256) void prep_kernel(const float* __restrict__ W, int COLS,
                                                   const float* __restrict__ stats,
                                                   const float* __restrict__ g,
                                                   const float* __restrict__ be, float invN,
                                                   unsigned short* __restrict__ Wt,
                                                   float* __restrict__ cvec) {
    __shared__ float sc[128], sh[128];
    int tid = threadIdx.x;
    if (tid < 128) {
        if (HASBN) {
            float mu  = stats[tid] * invN;
            float var = stats[128 + tid] * invN - mu * mu;
            float rs  = rsqrtf(var + BN_EPS);
            float s   = rs * g[tid];
            sc[tid] = s;
            sh[tid] = be[tid] - mu * s;
        } else { sc[tid] = 1.f; sh[tid] = 0.f; }
    }
    __syncthreads();
    int total = 128 * COLS;
    for (int idx = blockIdx.x * 256 + tid; idx < total; idx += gridDim.x * 256) {
        int k = idx / COLS, j = idx % COLS;
        Wt[j * 128 + k] = f2bf(sc[k] * W[idx]);
    }
    if (blockIdx.x == 0 && tid < COLS) {
        float a = 0.f;
        if (HASBN)
            for (int k = 0; k < 128; ++k) a += sh[k] * W[k * COLS + tid];
        cvec[tid] = a;
    }
}

// ---------------- GEMM: out[N,COLS](bf16) = H[N,128] @ Wt^T, MFMA bf16 ----------------

template <int COLS, bool IN_F32>
__global__ __launch_bounds__(256) void gemm_mfma(const void* __restrict__ Hin,
                                                 const unsigned short* __restrict__ Wt,
                                                 unsigned short* __restrict__ out, int N) {
    __shared__ unsigned short Hs[64][136];
    const int tid  = threadIdx.x;
    const int row0 = blockIdx.x * 64;

    if (IN_F32) {
        const float* H = (const float*)Hin;
#pragma unroll
        for (int it = 0; it < 8; ++it) {
            int idx = it * 256 + tid;
            int r = idx >> 5, c4 = (idx & 31) * 4;
            float4 v = {0.f, 0.f, 0.f, 0.f};
            if (row0 + r < N) v = *(const float4*)(H + (size_t)(row0 + r) * 128 + c4);
            Hs[r][c4 + 0] = f2bf(v.x); Hs[r][c4 + 1] = f2bf(v.y);
            Hs[r][c4 + 2] = f2bf(v.z); Hs[r][c4 + 3] = f2bf(v.w);
        }
    } else {
        const unsigned short* H = (const unsigned short*)Hin;
#pragma unroll
        for (int it = 0; it < 4; ++it) {
            int idx = it * 256 + tid;
            int r = idx >> 4, c8 = (idx & 15) * 8;
            uint4 v = {0u, 0u, 0u, 0u};
            if (row0 + r < N) v = *(const uint4*)(H + (size_t)(row0 + r) * 128 + c8);
            *(uint4*)&Hs[r][c8] = v;
        }
    }
    __syncthreads();

    const int lane = tid & 63, wave = tid >> 6;
    const int arow = lane & 15, kg = lane >> 4;
    const int r0   = wave * 16;

    bfrag af[4];
#pragma unroll
    for (int kc = 0; kc < 4; ++kc) af[kc] = *(const bfrag*)&Hs[r0 + arow][kc * 32 + kg * 8];

    constexpr int NT = COLS / 16;
    f32x4 acc[NT];
#pragma unroll
    for (int nt = 0; nt < NT; ++nt) acc[nt] = (f32x4){0.f, 0.f, 0.f, 0.f};

#pragma unroll
    for (int nt = 0; nt < NT; ++nt) {
        const unsigned short* wp = Wt + (size_t)(nt * 16 + arow) * 128 + kg * 8;
#pragma unroll
        for (int kc = 0; kc < 4; ++kc) {
            bfrag bf = *(const bfrag*)(wp + kc * 32);
            acc[nt] = __builtin_amdgcn_mfma_f32_16x16x32_bf16(af[kc], bf, acc[nt], 0, 0, 0);
        }
    }
    __syncthreads();

#pragma unroll
    for (int nt = 0; nt < NT; ++nt) {
        int col = nt * 16 + arow;
#pragma unroll
        for (int r = 0; r < 4; ++r)
            Hs[r0 + kg * 4 + r][col] = f2bf(acc[nt][r]);
    }
    __syncthreads();

    constexpr int CH = COLS / 8;
    for (int idx = tid; idx < 64 * CH; idx += 256) {
        int r = idx / CH, c8 = (idx % CH) * 8;
        if (row0 + r < N)
            *(uint4*)(out + (size_t)(row0 + r) * COLS + c8) = *(const uint4*)&Hs[r][c8];
    }
}

// ---------------- Aggregation: out = relu(agg(hw) + c*s + b), fused BN stats ----------------
// One tile of RPB rows per block. Edge records staged into LDS (sequential global reads),
// so the gather pipeline's vmcnt chain contains ONLY gathers: ping-pong 2x4 keeps
// 8 wave-gathers in flight per wave. Rare LDS-capacity overflow falls back to global.

template <int F, bool STATS, bool HASC, typename TOUT>
__global__ __launch_bounds__(256) void agg_kernel(const unsigned short* __restrict__ HW,
                                                  const int* __restrict__ rowptr,
                                                  const int2* __restrict__ epack,
                                                  const float* __restrict__ dinv,
                                                  const float* __restrict__ sarr,
                                                  const float* __restrict__ cvec,
                                                  const float* __restrict__ bias,
                                                  TOUT* __restrict__ out,
                                                  float* __restrict__ stats, int N) {
    constexpr int TPR = F / 8;      // lanes per row
    constexpr int RPB = 256 / TPR;  // rows per block tile
    constexpr int CAP = 1024;       // LDS edge-record capacity
    __shared__ int2 eld[CAP];

    const int tid  = threadIdx.x;
    const int lr   = tid / TPR;
    const int j8   = (tid % TPR) * 8;
    const int base = blockIdx.x * RPB;

    const int e0     = rowptr[base];
    const int eend   = rowptr[min(base + RPB, N)];
    const int estage = min(eend - e0, CAP);
    for (int i = tid; i < estage; i += 256) eld[i] = epack[e0 + i];
    __syncthreads();

    float ssum[8], ssq[8];
    if (STATS) {
#pragma unroll
        for (int k = 0; k < 8; ++k) { ssum[k] = 0.f; ssq[k] = 0.f; }
    }

    const int row = base + lr;
    if (row < N) {
        const int j0 = rowptr[row] - e0;      // LDS-relative
        const int j1 = rowptr[row + 1] - e0;

#define REC(jj) ((jj) < CAP ? eld[jj] : epack[e0 + (jj)])
#define LOADE(G, w, jj)                                            \
    do { int _j = (jj);                                            \
        if (_j < j1) { int2 _e = REC(_j);                          \
            w = __int_as_float(_e.y);                              \
            G = *(const uint4*)(HW + (size_t)_e.x * F + j8); }     \
    } while (0)
#define CONS(G, w, jj)                                             \
    do { if ((jj) < j1) fma8(G, w, acc); } while (0)

        uint4 A0, A1, A2, A3, B0, B1, B2, B3;
        float wa0, wa1, wa2, wa3, wb0, wb1, wb2, wb3;
        LOADE(A0, wa0, j0 + 0);
        LOADE(A1, wa1, j0 + 1);
        LOADE(A2, wa2, j0 + 2);
        LOADE(A3, wa3, j0 + 3);

        uint4 u = *(const uint4*)(HW + (size_t)row * F + j8);
        float di = dinv[row];
        float w0 = di * di;
        float acc[8];
        {
            float v[8];
            unpack8(u, v);
#pragma unroll
            for (int k = 0; k < 8; ++k) acc[k] = w0 * v[k];
        }

        for (int b = j0; b < j1; b += 8) {
            LOADE(B0, wb0, b + 4);
            LOADE(B1, wb1, b + 5);
            LOADE(B2, wb2, b + 6);
            LOADE(B3, wb3, b + 7);
            CONS(A0, wa0, b + 0);
            CONS(A1, wa1, b + 1);
            CONS(A2, wa2, b + 2);
            CONS(A3, wa3, b + 3);
            LOADE(A0, wa0, b + 8);
            LOADE(A1, wa1, b + 9);
            LOADE(A2, wa2, b + 10);
            LOADE(A3, wa3, b + 11);
            CONS(B0, wb0, b + 4);
            CONS(B1, wb1, b + 5);
            CONS(B2, wb2, b + 6);
            CONS(B3, wb3, b + 7);
        }
#undef REC
#undef LOADE
#undef CONS

        if (HASC) {
            float sv = sarr[row];
#pragma unroll
            for (int k = 0; k < 8; ++k) acc[k] += cvec[j8 + k] * sv;
        }
#pragma unroll
        for (int k = 0; k < 8; ++k) acc[k] = fmaxf(acc[k] + bias[j8 + k], 0.f);

        if constexpr (sizeof(TOUT) == 2) {
            unsigned int w0b = (unsigned int)f2bf(acc[0]) | ((unsigned int)f2bf(acc[1]) << 16);
            unsigned int w1b = (unsigned int)f2bf(acc[2]) | ((unsigned int)f2bf(acc[3]) << 16);
            unsigned int w2b = (unsigned int)f2bf(acc[4]) | ((unsigned int)f2bf(acc[5]) << 16);
            unsigned int w3b = (unsigned int)f2bf(acc[6]) | ((unsigned int)f2bf(acc[7]) << 16);
            uint4 o = {w0b, w1b, w2b, w3b};
            *(uint4*)((unsigned short*)out + (size_t)row * F + j8) = o;
        } else {
            float4 o0 = {acc[0], acc[1], acc[2], acc[3]};
            float4 o1 = {acc[4], acc[5], acc[6], acc[7]};
            *(float4*)((float*)out + (size_t)row * F + j8)     = o0;
            *(float4*)((float*)out + (size_t)row * F + j8 + 4) = o1;
        }
        if (STATS) {
#pragma unroll
            for (int k = 0; k < 8; ++k) {
                ssum[k] += acc[k];
                ssq[k]  += acc[k] * acc[k];
            }
        }
    }

    if constexpr (STATS) {
        __shared__ float red[RPB][F];
#pragma unroll
        for (int k = 0; k < 8; ++k) red[lr][j8 + k] = ssum[k];
        __syncthreads();
        if (tid < F) {
            float a = 0.f;
#pragma unroll
            for (int r = 0; r < RPB; ++r) a += red[r][tid];
            atomicAdd(&stats[tid], a);
        }
        __syncthreads();
#pragma unroll
        for (int k = 0; k < 8; ++k) red[lr][j8 + k] = ssq[k];
        __syncthreads();
        if (tid < F) {
            float a = 0.f;
#pragma unroll
            for (int r = 0; r < RPB; ++r) a += red[r][tid];
            atomicAdd(&stats[F + tid], a);
        }
    }
}

// ---------------- launch ----------------

extern "C" void kernel_launch(void* const* d_in, const int* in_sizes, int n_in,
                              void* d_out, int out_size, void* d_ws, size_t ws_size,
                              hipStream_t stream) {
    const float* x  = (const float*)d_in[0];
    const int*   ei = (const int*)d_in[1];
    const float* W1 = (const float*)d_in[2];  const float* b1 = (const float*)d_in[3];
    const float* W2 = (const float*)d_in[4];  const float* b2 = (const float*)d_in[5];
    const float* W3 = (const float*)d_in[6];  const float* b3 = (const float*)d_in[7];
    const float* W4 = (const float*)d_in[8];  const float* b4 = (const float*)d_in[9];
    const float* g1 = (const float*)d_in[10]; const float* be1 = (const float*)d_in[11];
    const float* g2 = (const float*)d_in[12]; const float* be2 = (const float*)d_in[13];
    const float* g3 = (const float*)d_in[14]; const float* be3 = (const float*)d_in[15];

    const int N = in_sizes[0] / 128;
    const int E = in_sizes[1] / 2;
    const int nblk = (N + 1023) / 1024;

    size_t off = 0;
    char* ws = (char*)d_ws;
    auto alloc = [&](size_t bytes) -> void* {
        void* p = ws + off;
        off += (bytes + 255) & ~(size_t)255;
        return p;
    };
    int*   cnt    = (int*)alloc((size_t)N * 4);
    float* dinv   = (float*)alloc((size_t)N * 4);
    int*   rowptr = (int*)alloc((size_t)(N + 1) * 4);
    int*   cursor = (int*)alloc((size_t)N * 4);
    int*   bsum   = (int*)alloc((size_t)nblk * 4);
    int*   boff   = (int*)alloc((size_t)(nblk + 1) * 4);
    int2*  epack  = (int2*)alloc((size_t)E * 8);
    float* sarr   = (float*)alloc((size_t)N * 4);
    float* stats  = (float*)alloc(256 * 4);
    unsigned short* Wt = (unsigned short*)alloc(128 * 128 * 2);
    float* cvec   = (float*)alloc(128 * 4);
    unsigned short* hA  = (unsigned short*)alloc((size_t)N * 128 * 2);
    unsigned short* hwB = (unsigned short*)alloc((size_t)N * 128 * 2);
    (void)ws_size; (void)n_in; (void)out_size;

    const int TB = 256;
    const int gE = (E + TB - 1) / TB;
    const int gN = (N + TB - 1) / TB;

    // CSR + norm + s[]
    hipMemsetAsync(cnt, 0, (size_t)N * 4, stream);
    count_kernel<<<gE, TB, 0, stream>>>(ei, E, cnt);
    dinv_kernel<<<gN, TB, 0, stream>>>(cnt, dinv, N);
    scan_blocks<<<nblk, 1024, 0, stream>>>(cnt, rowptr, bsum, N);
    scan_carry<<<1, 1, 0, stream>>>(bsum, boff, nblk);
    scan_add<<<gN, TB, 0, stream>>>(rowptr, boff, cursor, N, nblk);
    fill_kernel<<<gE, TB, 0, stream>>>(ei, E, cursor, dinv, epack);
    s_kernel<<<gN, TB, 0, stream>>>(rowptr, epack, dinv, sarr, N);

    const int gG   = (N + 63) / 64;
    const int gA16 = (N + 15) / 16;   // agg<128>: 16 rows/block
    const int gA32 = (N + 31) / 32;   // agg<64>: 32 rows/block
    const float invN = 1.0f / (float)N;

    // layer 1 (no BN fold; c=0)
    prep_kernel<false><<<8, 256, 0, stream>>>(W1, 128, nullptr, nullptr, nullptr, 0.f, Wt, cvec);
    gemm_mfma<128, true><<<gG, 256, 0, stream>>>(x, Wt, hwB, N);
    hipMemsetAsync(stats, 0, 256 * 4, stream);
    agg_kernel<128, true, false, unsigned short><<<gA16, 256, 0, stream>>>(
        hwB, rowptr, epack, dinv, sarr, cvec, b1, hA, stats, N);

    // layer 2
    prep_kernel<true><<<8, 256, 0, stream>>>(W2, 128, stats, g1, be1, invN, Wt, cvec);
    gemm_mfma<128, false><<<gG, 256, 0, stream>>>(hA, Wt, hwB, N);
    hipMemsetAsync(stats, 0, 256 * 4, stream);
    agg_kernel<128, true, true, unsigned short><<<gA16, 256, 0, stream>>>(
        hwB, rowptr, epack, dinv, sarr, cvec, b2, hA, stats, N);

    // layer 3
    prep_kernel<true><<<8, 256, 0, stream>>>(W3, 128, stats, g2, be2, invN, Wt, cvec);
    gemm_mfma<128, false><<<gG, 256, 0, stream>>>(hA, Wt, hwB, N);
    hipMemsetAsync(stats, 0, 256 * 4, stream);
    agg_kernel<128, true, true, unsigned short><<<gA16, 256, 0, stream>>>(
        hwB, rowptr, epack, dinv, sarr, cvec, b3, hA, stats, N);

    // layer 4 (COLS=64, f32 out, no stats)
    prep_kernel<true><<<8, 256, 0, stream>>>(W4, 64, stats, g3, be3, invN, Wt, cvec);
    gemm_mfma<64, false><<<gG, 256, 0, stream>>>(hA, Wt, hwB, N);
    agg_kernel<64, false, true, float><<<gA32, 256, 0, stream>>>(
        hwB, rowptr, epack, dinv, sarr, cvec, b4, (float*)d_out, nullptr, N);
}

// Round 6
// 461.287 us; speedup vs baseline: 1.6481x; 1.6481x over previous
//
#include <hip/hip_runtime.h>

#define BN_EPS 1e-5f

using bfrag = __attribute__((ext_vector_type(8))) short;
using f32x4 = __attribute__((ext_vector_type(4))) float;

__device__ inline float bf2f(unsigned int h16) {
    union { unsigned int u; float f; } v; v.u = h16 << 16; return v.f;
}
__device__ inline unsigned short f2bf(float f) {
    union { float f; unsigned int u; } v; v.f = f;
    unsigned int u = v.u;
    u += 0x7fffu + ((u >> 16) & 1u);
    return (unsigned short)(u >> 16);
}
__device__ inline void unpack8(uint4 u, float* f) {
    f[0] = bf2f(u.x & 0xffffu); f[1] = bf2f(u.x >> 16);
    f[2] = bf2f(u.y & 0xffffu); f[3] = bf2f(u.y >> 16);
    f[4] = bf2f(u.z & 0xffffu); f[5] = bf2f(u.z >> 16);
    f[6] = bf2f(u.w & 0xffffu); f[7] = bf2f(u.w >> 16);
}
__device__ inline void fma8(uint4 G, float w, float* acc) {
    float v[8];
    unpack8(G, v);
#pragma unroll
    for (int k = 0; k < 8; ++k) acc[k] += w * v[k];
}

// ---------------- CSR build (self-loops included as explicit edges) ----------------

__global__ void count_kernel(const int* __restrict__ ei, int E, int* __restrict__ cnt) {
    int e = blockIdx.x * blockDim.x + threadIdx.x;
    if (e < E) atomicAdd(&cnt[ei[E + e]], 1);
}

__global__ void dinv_kernel(const int* __restrict__ cnt, float* __restrict__ dinv, int N) {
    int i = blockIdx.x * blockDim.x + threadIdx.x;
    if (i < N) dinv[i] = rsqrtf((float)(cnt[i] + 1));  // +1 self loop
}

__global__ __launch_bounds__(1024) void scan_blocks(const int* __restrict__ cnt,
                                                    int* __restrict__ rowptr,
                                                    int* __restrict__ bsum, int N) {
    __shared__ int sh[1024];
    int t = threadIdx.x;
    int i = blockIdx.x * 1024 + t;
    int v = (i < N) ? cnt[i] + 1 : 0;   // +1: self-loop record
    sh[t] = v;
    __syncthreads();
    for (int off = 1; off < 1024; off <<= 1) {
        int x = (t >= off) ? sh[t - off] : 0;
        __syncthreads();
        sh[t] += x;
        __syncthreads();
    }
    if (i < N) rowptr[i] = sh[t] - v;
    if (t == 1023) bsum[blockIdx.x] = sh[1023];
}

__global__ void scan_carry(const int* __restrict__ bsum, int* __restrict__ boff, int nblk) {
    if (threadIdx.x == 0 && blockIdx.x == 0) {
        int run = 0;
        for (int b = 0; b < nblk; ++b) { int v = bsum[b]; boff[b] = run; run += v; }
        boff[nblk] = run;
    }
}

__global__ void scan_add(int* __restrict__ rowptr, const int* __restrict__ boff,
                         int* __restrict__ cursor, int N, int nblk) {
    int i = blockIdx.x * blockDim.x + threadIdx.x;
    if (i < N) {
        int v = rowptr[i] + boff[i >> 10];
        rowptr[i] = v;
        cursor[i] = v;
    }
    if (i == 0) rowptr[N] = boff[nblk];
}

__global__ void fill_kernel(const int* __restrict__ ei, int E, int* __restrict__ cursor,
                            const float* __restrict__ dinv, int2* __restrict__ epack) {
    int e = blockIdx.x * blockDim.x + threadIdx.x;
    if (e < E) {
        int s = ei[e], d = ei[E + e];
        int p = atomicAdd(&cursor[d], 1);
        float nrm = dinv[s] * dinv[d];
        epack[p] = make_int2(s, __float_as_int(nrm));
    }
}

__global__ void self_kernel(int N, int* __restrict__ cursor, const float* __restrict__ dinv,
                            int2* __restrict__ epack) {
    int i = blockIdx.x * blockDim.x + threadIdx.x;
    if (i < N) {
        int p = atomicAdd(&cursor[i], 1);
        float w = dinv[i] * dinv[i];
        epack[p] = make_int2(i, __float_as_int(w));
    }
}

__global__ void s_kernel(const int* __restrict__ rowptr, const int2* __restrict__ epack,
                         float* __restrict__ sarr, int N) {
    int i = blockIdx.x * blockDim.x + threadIdx.x;
    if (i < N) {
        float a = 0.f;
        int j1 = rowptr[i + 1];
        for (int j = rowptr[i]; j < j1; ++j) a += __int_as_float(epack[j].y);
        sarr[i] = a;
    }
}

// ---------------- per-layer weight prep: Wt[j][k] = bf16(scale[k]*W[k][j]), c[j]=shift@W ----------------

template <bool HASBN>
__global__ __launch_bounds__(256) void prep_kernel(const float* __restrict__ W, int COLS,
                                                   const float* __restrict__ stats,
                                                   const float* __restrict__ g,
                                                   const float* __restrict__ be, float invN,
                                                   unsigned short* __restrict__ Wt,
                                                   float* __restrict__ cvec) {
    __shared__ float sc[128], sh[128];
    int tid = threadIdx.x;
    if (tid < 128) {
        if (HASBN) {
            float mu  = stats[tid] * invN;
            float var = stats[128 + tid] * invN - mu * mu;
            float rs  = rsqrtf(var + BN_EPS);
            float s   = rs * g[tid];
            sc[tid] = s;
            sh[tid] = be[tid] - mu * s;
        } else { sc[tid] = 1.f; sh[tid] = 0.f; }
    }
    __syncthreads();
    int total = 128 * COLS;
    for (int idx = blockIdx.x * 256 + tid; idx < total; idx += gridDim.x * 256) {
        int k = idx / COLS, j = idx % COLS;
        Wt[j * 128 + k] = f2bf(sc[k] * W[idx]);
    }
    if (blockIdx.x == 0 && tid < COLS) {
        float a = 0.f;
        if (HASBN)
            for (int k = 0; k < 128; ++k) a += sh[k] * W[k * COLS + tid];
        cvec[tid] = a;
    }
}

// ---------------- GEMM: out[N,COLS](bf16) = H[N,128] @ Wt^T, MFMA bf16 ----------------

template <int COLS, bool IN_F32>
__global__ __launch_bounds__(256) void gemm_mfma(const void* __restrict__ Hin,
                                                 const unsigned short* __restrict__ Wt,
                                                 unsigned short* __restrict__ out, int N) {
    __shared__ unsigned short Hs[64][136];
    const int tid  = threadIdx.x;
    const int row0 = blockIdx.x * 64;

    if (IN_F32) {
        const float* H = (const float*)Hin;
#pragma unroll
        for (int it = 0; it < 8; ++it) {
            int idx = it * 256 + tid;
            int r = idx >> 5, c4 = (idx & 31) * 4;
            float4 v = {0.f, 0.f, 0.f, 0.f};
            if (row0 + r < N) v = *(const float4*)(H + (size_t)(row0 + r) * 128 + c4);
            Hs[r][c4 + 0] = f2bf(v.x); Hs[r][c4 + 1] = f2bf(v.y);
            Hs[r][c4 + 2] = f2bf(v.z); Hs[r][c4 + 3] = f2bf(v.w);
        }
    } else {
        const unsigned short* H = (const unsigned short*)Hin;
#pragma unroll
        for (int it = 0; it < 4; ++it) {
            int idx = it * 256 + tid;
            int r = idx >> 4, c8 = (idx & 15) * 8;
            uint4 v = {0u, 0u, 0u, 0u};
            if (row0 + r < N) v = *(const uint4*)(H + (size_t)(row0 + r) * 128 + c8);
            *(uint4*)&Hs[r][c8] = v;
        }
    }
    __syncthreads();

    const int lane = tid & 63, wave = tid >> 6;
    const int arow = lane & 15, kg = lane >> 4;
    const int r0   = wave * 16;

    bfrag af[4];
#pragma unroll
    for (int kc = 0; kc < 4; ++kc) af[kc] = *(const bfrag*)&Hs[r0 + arow][kc * 32 + kg * 8];

    constexpr int NT = COLS / 16;
    f32x4 acc[NT];
#pragma unroll
    for (int nt = 0; nt < NT; ++nt) acc[nt] = (f32x4){0.f, 0.f, 0.f, 0.f};

#pragma unroll
    for (int nt = 0; nt < NT; ++nt) {
        const unsigned short* wp = Wt + (size_t)(nt * 16 + arow) * 128 + kg * 8;
#pragma unroll
        for (int kc = 0; kc < 4; ++kc) {
            bfrag bf = *(const bfrag*)(wp + kc * 32);
            acc[nt] = __builtin_amdgcn_mfma_f32_16x16x32_bf16(af[kc], bf, acc[nt], 0, 0, 0);
        }
    }
    __syncthreads();

#pragma unroll
    for (int nt = 0; nt < NT; ++nt) {
        int col = nt * 16 + arow;
#pragma unroll
        for (int r = 0; r < 4; ++r)
            Hs[r0 + kg * 4 + r][col] = f2bf(acc[nt][r]);
    }
    __syncthreads();

    constexpr int CH = COLS / 8;
    for (int idx = tid; idx < 64 * CH; idx += 256) {
        int r = idx / CH, c8 = (idx % CH) * 8;
        if (row0 + r < N)
            *(uint4*)(out + (size_t)(row0 + r) * COLS + c8) = *(const uint4*)&Hs[r][c8];
    }
}

// ---------------- Aggregation: edge-stream, 3-stage pipeline ----------------

template <int F, bool STATS, bool HASC, typename TOUT, int RG>
__global__ __launch_bounds__(256) void agg_kernel(const unsigned short* __restrict__ HW,
                                                  const int* __restrict__ rowptr,
                                                  const int2* __restrict__ epack,
                                                  const float* __restrict__ sarr,
                                                  const float* __restrict__ cvec,
                                                  const float* __restrict__ bias,
                                                  TOUT* __restrict__ out,
                                                  float* __restrict__ stats, int N) {
    constexpr int TPR  = F / 8;      // lanes per row-group
    constexpr int NGRP = 256 / TPR;  // groups per block
    const int tid = threadIdx.x;
    const int grp = tid / TPR;
    const int j8  = (tid % TPR) * 8;
    const int r0  = (blockIdx.x * NGRP + grp) * RG;

    float ssum[8], ssq[8];
    if (STATS) {
#pragma unroll
        for (int k = 0; k < 8; ++k) { ssum[k] = 0.f; ssq[k] = 0.f; }
    }

    if (r0 < N) {
        float b8[8], c8[8];
#pragma unroll
        for (int k = 0; k < 8; ++k) b8[k] = bias[j8 + k];
        if (HASC) {
#pragma unroll
            for (int k = 0; k < 8; ++k) c8[k] = cvec[j8 + k];
        }

        const int e0 = rowptr[r0];
        int bound = rowptr[min(r0 + 1, N)];
        int bnd2  = rowptr[min(r0 + 2, N)];
        int bnd3  = rowptr[min(r0 + 3, N)];
        int bnd4  = rowptr[min(r0 + 4, N)];
        const int eend = bnd4;           // RG == 4
        float sv = 0.f, sv2 = 0.f, sv3 = 0.f, sv4 = 0.f;
        if (HASC) {
            sv  = sarr[r0];
            sv2 = sarr[min(r0 + 1, N - 1)];
            sv3 = sarr[min(r0 + 2, N - 1)];
            sv4 = sarr[min(r0 + 3, N - 1)];
        }
        int r = r0;

        float acc[8];
#pragma unroll
        for (int k = 0; k < 8; ++k) acc[k] = 0.f;

#define FLUSH()                                                               \
    do {                                                                      \
        if (HASC) {                                                           \
            _Pragma("unroll") for (int k = 0; k < 8; ++k) acc[k] += c8[k] * sv; \
        }                                                                     \
        _Pragma("unroll") for (int k = 0; k < 8; ++k)                         \
            acc[k] = fmaxf(acc[k] + b8[k], 0.f);                              \
        if constexpr (sizeof(TOUT) == 2) {                                    \
            unsigned int p0 = (unsigned int)f2bf(acc[0]) | ((unsigned int)f2bf(acc[1]) << 16); \
            unsigned int p1 = (unsigned int)f2bf(acc[2]) | ((unsigned int)f2bf(acc[3]) << 16); \
            unsigned int p2 = (unsigned int)f2bf(acc[4]) | ((unsigned int)f2bf(acc[5]) << 16); \
            unsigned int p3 = (unsigned int)f2bf(acc[6]) | ((unsigned int)f2bf(acc[7]) << 16); \
            uint4 o = {p0, p1, p2, p3};                                       \
            *(uint4*)((unsigned short*)out + (size_t)r * F + j8) = o;         \
        } else {                                                              \
            float4 o0 = {acc[0], acc[1], acc[2], acc[3]};                     \
            float4 o1 = {acc[4], acc[5], acc[6], acc[7]};                     \
            *(float4*)((float*)out + (size_t)r * F + j8)     = o0;            \
            *(float4*)((float*)out + (size_t)r * F + j8 + 4) = o1;            \
        }                                                                     \
        if (STATS) {                                                          \
            _Pragma("unroll") for (int k = 0; k < 8; ++k) {                   \
                ssum[k] += acc[k];                                            \
                ssq[k]  += acc[k] * acc[k];                                   \
            }                                                                 \
        }                                                                     \
        _Pragma("unroll") for (int k = 0; k < 8; ++k) acc[k] = 0.f;           \
        sv = sv2; sv2 = sv3; sv3 = sv4;                                       \
        bound = bnd2; bnd2 = bnd3; bnd3 = bnd4;                               \
    } while (0)

#define EPLOAD(ss, ww, ii)                                                    \
    do { int _i = (ii);                                                       \
        if (_i < eend) { int2 _e = epack[_i];                                 \
            ss = _e.x; ww = __int_as_float(_e.y); }                           \
    } while (0)

#define GISS(G, gw, ss, ww)                                                   \
    do { G = *(const uint4*)(HW + (size_t)(ss) * F + j8); gw = (ww); } while (0)

#define CONS1(G, gw, ii)                                                      \
    do { int _c = (ii);                                                       \
        if (_c < eend) {                                                      \
            if (_c >= bound) { FLUSH(); ++r; }                                \
            fma8(G, gw, acc);                                                 \
        }                                                                     \
    } while (0)

        int sA0 = 0, sA1 = 0, sA2 = 0, sA3 = 0, sB0 = 0, sB1 = 0, sB2 = 0, sB3 = 0;
        float wA0 = 0, wA1 = 0, wA2 = 0, wA3 = 0, wB0 = 0, wB1 = 0, wB2 = 0, wB3 = 0;
        uint4 GA0 = {}, GA1 = {}, GA2 = {}, GA3 = {}, GB0 = {}, GB1 = {}, GB2 = {}, GB3 = {};
        float ga0 = 0, ga1 = 0, ga2 = 0, ga3 = 0, gb0 = 0, gb1 = 0, gb2 = 0, gb3 = 0;

        EPLOAD(sA0, wA0, e0 + 0); EPLOAD(sA1, wA1, e0 + 1);
        EPLOAD(sA2, wA2, e0 + 2); EPLOAD(sA3, wA3, e0 + 3);
        EPLOAD(sB0, wB0, e0 + 4); EPLOAD(sB1, wB1, e0 + 5);
        EPLOAD(sB2, wB2, e0 + 6); EPLOAD(sB3, wB3, e0 + 7);
        GISS(GA0, ga0, sA0, wA0); GISS(GA1, ga1, sA1, wA1);
        GISS(GA2, ga2, sA2, wA2); GISS(GA3, ga3, sA3, wA3);

        for (int b = e0; b < eend; b += 8) {
            EPLOAD(sA0, wA0, b + 8);  EPLOAD(sA1, wA1, b + 9);
            EPLOAD(sA2, wA2, b + 10); EPLOAD(sA3, wA3, b + 11);
            GISS(GB0, gb0, sB0, wB0); GISS(GB1, gb1, sB1, wB1);
            GISS(GB2, gb2, sB2, wB2); GISS(GB3, gb3, sB3, wB3);
            CONS1(GA0, ga0, b + 0); CONS1(GA1, ga1, b + 1);
            CONS1(GA2, ga2, b + 2); CONS1(GA3, ga3, b + 3);

            EPLOAD(sB0, wB0, b + 12); EPLOAD(sB1, wB1, b + 13);
            EPLOAD(sB2, wB2, b + 14); EPLOAD(sB3, wB3, b + 15);
            GISS(GA0, ga0, sA0, wA0); GISS(GA1, ga1, sA1, wA1);
            GISS(GA2, ga2, sA2, wA2); GISS(GA3, ga3, sA3, wA3);
            CONS1(GB0, gb0, b + 4); CONS1(GB1, gb1, b + 5);
            CONS1(GB2, gb2, b + 6); CONS1(GB3, gb3, b + 7);
        }
        FLUSH();   // last row of the group

#undef FLUSH
#undef EPLOAD
#undef GISS
#undef CONS1
    }

    if constexpr (STATS) {
        __shared__ float red[NGRP][F];
#pragma unroll
        for (int k = 0; k < 8; ++k) red[grp][j8 + k] = ssum[k];
        __syncthreads();
        if (tid < F) {
            float a = 0.f;
#pragma unroll
            for (int g = 0; g < NGRP; ++g) a += red[g][tid];
            atomicAdd(&stats[tid], a);
        }
        __syncthreads();
#pragma unroll
        for (int k = 0; k < 8; ++k) red[grp][j8 + k] = ssq[k];
        __syncthreads();
        if (tid < F) {
            float a = 0.f;
#pragma unroll
            for (int g = 0; g < NGRP; ++g) a += red[g][tid];
            atomicAdd(&stats[F + tid], a);
        }
    }
}

// ---------------- launch ----------------

extern "C" void kernel_launch(void* const* d_in, const int* in_sizes, int n_in,
                              void* d_out, int out_size, void* d_ws, size_t ws_size,
                              hipStream_t stream) {
    const float* x  = (const float*)d_in[0];
    const int*   ei = (const int*)d_in[1];
    const float* W1 = (const float*)d_in[2];  const float* b1 = (const float*)d_in[3];
    const float* W2 = (const float*)d_in[4];  const float* b2 = (const float*)d_in[5];
    const float* W3 = (const float*)d_in[6];  const float* b3 = (const float*)d_in[7];
    const float* W4 = (const float*)d_in[8];  const float* b4 = (const float*)d_in[9];
    const float* g1 = (const float*)d_in[10]; const float* be1 = (const float*)d_in[11];
    const float* g2 = (const float*)d_in[12]; const float* be2 = (const float*)d_in[13];
    const float* g3 = (const float*)d_in[14]; const float* be3 = (const float*)d_in[15];

    const int N = in_sizes[0] / 128;
    const int E = in_sizes[1] / 2;
    const int nblk = (N + 1023) / 1024;

    size_t off = 0;
    char* ws = (char*)d_ws;
    auto alloc = [&](size_t bytes) -> void* {
        void* p = ws + off;
        off += (bytes + 255) & ~(size_t)255;
        return p;
    };
    int*   cnt    = (int*)alloc((size_t)N * 4);
    float* dinv   = (float*)alloc((size_t)N * 4);
    int*   rowptr = (int*)alloc((size_t)(N + 1) * 4);
    int*   cursor = (int*)alloc((size_t)N * 4);
    int*   bsum   = (int*)alloc((size_t)nblk * 4);
    int*   boff   = (int*)alloc((size_t)(nblk + 1) * 4);
    int2*  epack  = (int2*)alloc((size_t)(E + N) * 8);
    float* sarr   = (float*)alloc((size_t)N * 4);
    float* stats  = (float*)alloc(256 * 4);
    unsigned short* Wt = (unsigned short*)alloc(128 * 128 * 2);
    float* cvec   = (float*)alloc(128 * 4);
    unsigned short* hA  = (unsigned short*)alloc((size_t)N * 128 * 2);
    unsigned short* hwB = (unsigned short*)alloc((size_t)N * 128 * 2);
    (void)ws_size; (void)n_in; (void)out_size;

    const int TB = 256;
    const int gE = (E + TB - 1) / TB;
    const int gN = (N + TB - 1) / TB;

    // CSR + norm + s[]
    hipMemsetAsync(cnt, 0, (size_t)N * 4, stream);
    count_kernel<<<gE, TB, 0, stream>>>(ei, E, cnt);
    dinv_kernel<<<gN, TB, 0, stream>>>(cnt, dinv, N);
    scan_blocks<<<nblk, 1024, 0, stream>>>(cnt, rowptr, bsum, N);
    scan_carry<<<1, 1, 0, stream>>>(bsum, boff, nblk);
    scan_add<<<gN, TB, 0, stream>>>(rowptr, boff, cursor, N, nblk);
    fill_kernel<<<gE, TB, 0, stream>>>(ei, E, cursor, dinv, epack);
    self_kernel<<<gN, TB, 0, stream>>>(N, cursor, dinv, epack);
    s_kernel<<<gN, TB, 0, stream>>>(rowptr, epack, sarr, N);

    const int gG    = (N + 63) / 64;
    const int gA128 = (N + 63) / 64;    // agg<128>: 16 groups * 4 rows
    const int gA64  = (N + 127) / 128;  // agg<64>: 32 groups * 4 rows
    const float invN = 1.0f / (float)N;

    // layer 1 (no BN fold; c=0)
    prep_kernel<false><<<8, 256, 0, stream>>>(W1, 128, nullptr, nullptr, nullptr, 0.f, Wt, cvec);
    gemm_mfma<128, true><<<gG, 256, 0, stream>>>(x, Wt, hwB, N);
    hipMemsetAsync(stats, 0, 256 * 4, stream);
    agg_kernel<128, true, false, unsigned short, 4><<<gA128, 256, 0, stream>>>(
        hwB, rowptr, epack, sarr, cvec, b1, hA, stats, N);

    // layer 2
    prep_kernel<true><<<8, 256, 0, stream>>>(W2, 128, stats, g1, be1, invN, Wt, cvec);
    gemm_mfma<128, false><<<gG, 256, 0, stream>>>(hA, Wt, hwB, N);
    hipMemsetAsync(stats, 0, 256 * 4, stream);
    agg_kernel<128, true, true, unsigned short, 4><<<gA128, 256, 0, stream>>>(
        hwB, rowptr, epack, sarr, cvec, b2, hA, stats, N);

    // layer 3
    prep_kernel<true><<<8, 256, 0, stream>>>(W3, 128, stats, g2, be2, invN, Wt, cvec);
    gemm_mfma<128, false><<<gG, 256, 0, stream>>>(hA, Wt, hwB, N);
    hipMemsetAsync(stats, 0, 256 * 4, stream);
    agg_kernel<128, true, true, unsigned short, 4><<<gA128, 256, 0, stream>>>(
        hwB, rowptr, epack, sarr, cvec, b3, hA, stats, N);

    // layer 4 (COLS=64, f32 out, no stats)
    prep_kernel<true><<<8, 256, 0, stream>>>(W4, 64, stats, g3, be3, invN, Wt, cvec);
    gemm_mfma<64, false><<<gG, 256, 0, stream>>>(hA, Wt, hwB, N);
    agg_kernel<64, false, true, float, 4><<<gA64, 256, 0, stream>>>(
        hwB, rowptr, epack, sarr, cvec, b4, (float*)d_out, nullptr, N);
}